// Round 22
// baseline (102.930 us; speedup 1.0000x reference)
//
#include <hip/hip_runtime.h>

// B=4, N=1024, E=1024, H=16, D=64.  bf16 MFMA (16x16x32), fp32 accum.
// Raw-reshape: per batch-head bh, Q/K/V slab = flat [bh*65536, +65536) viewed [1024 n][64 d].
// GEMMs (r22): 128x128 tile, 3-buffer LDS ring (depth-2 prefetch, vmcnt(8)), granule-XOR
// swizzle (T2), setprio (T5), and NEW: 2D L2-BLOCKED XCD CHUNKING — each XCD owns an
// 8Mx12N chunk (MODE 0; 4Mx8N MODE 1) walked M-fastest, active set ~2.3MB < 4MB L2
// (r17 FETCH showed 2x over-fetch from the old 4Mx24N strip whose 6MB B-set thrashed L2).
// Q PRE-SCALED by 0.125*log2(e) -> exp2 softmax. transpose_v builds V^T per head.
// Attention (r20, unchanged): 16 q-rows/wave, 64-row panels, 1024 blocks (4/CU),
// K/V^T in double-buffered LDS (counted vmcnt(4)), XOR-swizzled ds_read_b128,
// no split-K/merge, LPT + XCD pinning.

typedef __bf16 bf16x8 __attribute__((ext_vector_type(8)));
typedef float f32x4 __attribute__((ext_vector_type(4)));

#define QSCALE 0.18033688011112042f   // 0.125 * log2(e)
#define DEFER_THR 11.0f               // log2 domain; P bounded by 2^11

__device__ __forceinline__ unsigned short f2bf(float f) {
    unsigned u = __float_as_uint(f);
    u += 0x7fffu + ((u >> 16) & 1u);   // round-to-nearest-even
    return (unsigned short)(u >> 16);
}

__device__ __forceinline__ unsigned cvtpk_bf16(float lo, float hi) {
    unsigned r;
    asm("v_cvt_pk_bf16_f32 %0, %1, %2" : "=v"(r) : "v"(lo), "v"(hi));
    return r;
}

union FragU { uint4 u; bf16x8 v; };

__device__ __forceinline__ bf16x8 ld_frag(const unsigned short* p) {
    FragU x; x.u = *(const uint4*)p; return x.v;
}

__device__ __forceinline__ void gload_lds16(const void* g, void* l) {
    __builtin_amdgcn_global_load_lds(
        (const __attribute__((address_space(1))) void*)g,
        (__attribute__((address_space(3))) void*)l, 16, 0, 0);
}

// ---------------- fused prep: x->bf16 + both weight transposes (one launch) ----------------
__global__ __launch_bounds__(256) void prep(
    const float* __restrict__ x,    unsigned short* __restrict__ xb,
    const float* __restrict__ Wqkv, unsigned short* __restrict__ wqkvT,
    const float* __restrict__ Wfc,  unsigned short* __restrict__ wfcT)
{
    __shared__ float tile[32][33];
    int bid = blockIdx.x;
    int tx = threadIdx.x & 31, ty = threadIdx.x >> 5;   // (32,8)
    if (bid < 3072) {
        int c0 = (bid % 96) * 32, r0 = (bid / 96) * 32;
        for (int i = ty; i < 32; i += 8)
            tile[i][tx] = Wqkv[(r0 + i) * 3072 + c0 + tx];
        __syncthreads();
        for (int i = ty; i < 32; i += 8)
            wqkvT[(long)(c0 + i) * 1024 + r0 + tx] = f2bf(tile[tx][i]);
    } else if (bid < 4096) {
        int b2 = bid - 3072;
        int c0 = (b2 % 32) * 32, r0 = (b2 / 32) * 32;
        for (int i = ty; i < 32; i += 8)
            tile[i][tx] = Wfc[(r0 + i) * 1024 + c0 + tx];
        __syncthreads();
        for (int i = ty; i < 32; i += 8)
            wfcT[(long)(c0 + i) * 1024 + r0 + tx] = f2bf(tile[tx][i]);
    } else {
        const int n4 = 1 << 20;
        for (int i = (bid - 4096) * 256 + threadIdx.x; i < n4; i += 1024 * 256) {
            float4 f = ((const float4*)x)[i];
            unsigned a = (unsigned)f2bf(f.x) | ((unsigned)f2bf(f.y) << 16);
            unsigned b = (unsigned)f2bf(f.z) | ((unsigned)f2bf(f.w) << 16);
            ((uint2*)xb)[i] = make_uint2(a, b);
        }
    }
}

// ---------------- per-head V transpose: [1024 n][64 d] -> [64 d][1024 n] ----------------
__global__ void transpose_v(const unsigned short* __restrict__ v,
                            unsigned short* __restrict__ vt) {
    __shared__ unsigned short tile[32][33];
    int bh = blockIdx.z;
    int n0 = blockIdx.x * 32, d0 = blockIdx.y * 32;
    const unsigned short* src = v + (long)bh * 65536;
    unsigned short* dst = vt + (long)bh * 65536;
    for (int i = threadIdx.y; i < 32; i += 8)
        tile[i][threadIdx.x] = src[(n0 + i) * 64 + d0 + threadIdx.x];
    __syncthreads();
    for (int i = threadIdx.y; i < 32; i += 8)
        dst[(d0 + i) * 1024 + n0 + threadIdx.x] = tile[threadIdx.x][i];
}

// ---------------- bf16 GEMM, 128x128 tile, 3-buffer ring + 2D L2-blocked XCD chunks ----------------
// Per K-step: vmcnt(8) [tile t landed; t+1,t+2 in flight] -> barrier -> ds_read(swizzled)
// + MFMA(setprio) -> barrier [reads done] -> STAGE(t+3) into just-read buffer.
template <int MODE>
__global__ __launch_bounds__(256) void gemm128(
    const unsigned short* __restrict__ A,    // [M,1024] bf16
    const unsigned short* __restrict__ Bt,   // [N,1024] bf16
    const float* __restrict__ bias,          // [N]
    unsigned short* __restrict__ qb,
    unsigned short* __restrict__ kb,
    unsigned short* __restrict__ vb,
    float* __restrict__ outf)
{
    __shared__ unsigned short As[3][4096];   // [128 rows][32 k], rows = 64B = 4 granules
    __shared__ unsigned short Bs[3][4096];
    int t = threadIdx.x, lane = t & 63, w = t >> 6;
    int wm = w >> 1, wn = w & 1;
    int lrow = lane >> 4, lcol = lane & 15;

    // 2D L2-blocked chunking: each XCD owns a contiguous (CM x CN) tile chunk,
    // walked M-fastest (active set ~1 B-panel + CM A-panels, L2-resident).
    int id = blockIdx.x;
    int xcd = id & 7, s_ = id >> 3;
    int tm0, tn0;
    if (MODE == 0) {
        // grid 768 = 32M x 24N; chunk 8M x 12N; chunk grid 4 x 2
        int cr = xcd >> 1, cc = xcd & 1;
        int m_sub = s_ & 7, n_sub = s_ >> 3;          // s_ in 0..95, n_sub 0..11
        tm0 = (cr * 8 + m_sub) * 128;
        tn0 = (cc * 12 + n_sub) * 128;
    } else {
        // grid 256 = 32M x 8N; chunk 4M x 8N; chunk grid 8 x 1
        int m_sub = s_ & 3, n_sub = s_ >> 2;          // s_ in 0..31, n_sub 0..7
        tm0 = (xcd * 4 + m_sub) * 128;
        tn0 = n_sub * 128;
    }

    int off0 = w * 1024 + lane * 16, off1 = 4096 + w * 1024 + lane * 16;
    int r0 = (off0 & 4095) >> 6, g0 = ((((off0 >> 4) & 3) ^ ((r0 >> 1) & 3)) << 4);
    int r1 = (off1 & 4095) >> 6, g1 = ((((off1 >> 4) & 3) ^ ((r1 >> 1) & 3)) << 4);
    r1 += 64;

    const char* pA0 = (const char*)A  + (long)(tm0 + r0) * 2048 + g0;
    const char* pA1 = (const char*)A  + (long)(tm0 + r1) * 2048 + g1;
    const char* pB0 = (const char*)Bt + (long)(tn0 + r0) * 2048 + g0;
    const char* pB1 = (const char*)Bt + (long)(tn0 + r1) * 2048 + g1;

    int aoff[4], boff[4];
    #pragma unroll
    for (int mi = 0; mi < 4; ++mi) {
        int row = wm * 64 + mi * 16 + lcol;
        aoff[mi] = row * 32 + ((lrow ^ ((row >> 1) & 3)) << 3);
    }
    #pragma unroll
    for (int ni = 0; ni < 4; ++ni) {
        int row = wn * 64 + ni * 16 + lcol;
        boff[ni] = row * 32 + ((lrow ^ ((row >> 1) & 3)) << 3);
    }

    f32x4 acc[4][4] = {};

    auto STAGE = [&](int buf, int kt) {
        long kby = (long)kt * 2;
        gload_lds16(pA0 + kby, (char*)&As[buf][0] + w * 1024);
        gload_lds16(pA1 + kby, (char*)&As[buf][0] + 4096 + w * 1024);
        gload_lds16(pB0 + kby, (char*)&Bs[buf][0] + w * 1024);
        gload_lds16(pB1 + kby, (char*)&Bs[buf][0] + 4096 + w * 1024);
    };

    STAGE(0, 0);
    STAGE(1, 32);
    STAGE(2, 64);

    int cur = 0;
    for (int tt = 0; tt < 32; ++tt) {
        if (tt < 30)      asm volatile("s_waitcnt vmcnt(8)" ::: "memory");
        else if (tt == 30) asm volatile("s_waitcnt vmcnt(4)" ::: "memory");
        else               asm volatile("s_waitcnt vmcnt(0)" ::: "memory");
        __builtin_amdgcn_s_barrier();          // tile tt landed for all waves

        bf16x8 af[4], bfr[4];
        #pragma unroll
        for (int mi = 0; mi < 4; ++mi) af[mi] = ld_frag(&As[cur][aoff[mi]]);
        #pragma unroll
        for (int ni = 0; ni < 4; ++ni) bfr[ni] = ld_frag(&Bs[cur][boff[ni]]);
        __builtin_amdgcn_s_setprio(1);
        #pragma unroll
        for (int mi = 0; mi < 4; ++mi)
            #pragma unroll
            for (int ni = 0; ni < 4; ++ni)
                acc[mi][ni] = __builtin_amdgcn_mfma_f32_16x16x32_bf16(af[mi], bfr[ni], acc[mi][ni], 0, 0, 0);
        __builtin_amdgcn_s_setprio(0);

        __builtin_amdgcn_s_barrier();          // all reads of buf[cur] done
        if (tt + 3 < 32) STAGE(cur, (tt + 3) * 32);
        cur = (cur == 2) ? 0 : cur + 1;
    }

    #pragma unroll
    for (int mi = 0; mi < 4; ++mi) {
        int gr0 = tm0 + wm * 64 + mi * 16 + lrow * 4;
        #pragma unroll
        for (int ni = 0; ni < 4; ++ni) {
            int gc = tn0 + wn * 64 + ni * 16 + lcol;
            float bv = bias[gc];
            if (MODE == 0) {
                int sec = gc >> 10, ei = gc & 1023;
                unsigned short* dst = sec == 0 ? qb : (sec == 1 ? kb : vb);
                if (sec == 0) {
                    #pragma unroll
                    for (int r = 0; r < 4; ++r)
                        dst[(long)(gr0 + r) * 1024 + ei] = f2bf((acc[mi][ni][r] + bv) * QSCALE);
                } else {
                    #pragma unroll
                    for (int r = 0; r < 4; ++r)
                        dst[(long)(gr0 + r) * 1024 + ei] = f2bf(acc[mi][ni][r] + bv);
                }
            } else {
                #pragma unroll
                for (int r = 0; r < 4; ++r)
                    outf[(long)(gr0 + r) * 1024 + gc] = acc[mi][ni][r] + bv;
            }
        }
    }
}

// ---------------- flash attention: shared-LDS K/V walk, 4 waves x 16 q-rows (r20) ----------------
__global__ __launch_bounds__(256) void attn(
    const unsigned short* __restrict__ qbuf,
    const unsigned short* __restrict__ kbuf,
    const unsigned short* __restrict__ vtbuf,
    unsigned short* __restrict__ obuf)
{
    __shared__ unsigned short Ks[2][4096];   // [64 k][64 d], swizzled
    __shared__ unsigned short Vs[2][4096];   // [64 d][64 k], swizzled
    __shared__ unsigned short Ps[4][16][40]; // per-wave P (16 q-rows)

    int id = blockIdx.x;
    int xcd = id & 7, s_ = id >> 3;          // s_ in 0..127
    int j  = 15 - (s_ >> 3);                 // panels descending (LPT: long first)
    int bh = xcd + 8 * (s_ & 7);             // bh pinned to XCD

    const char* Kb = (const char*)(kbuf + (long)bh * 65536);
    const char* Vb = (const char*)(vtbuf + (long)bh * 65536);
    const unsigned short* Q = qbuf + (long)bh * 65536;
    unsigned short* O = obuf + (long)bh * 65536;

    int t = threadIdx.x, lane = t & 63, w = t >> 6;
    int lrow = lane >> 4, lcol = lane & 15;
    const float NEG = -__builtin_inff();

    int qbase = j * 64 + w * 16;             // wave's 16 q-rows
    int T = j + 1;                           // 64-key tiles for this panel

    int row0 = w * 8 + (lane >> 3);
    int slot = (((lane & 7) ^ (lane >> 3)) << 4);

    auto STAGE = [&](int buf, int kt) {
        long k2 = (long)kt * 2;
        gload_lds16(Kb + (k2 + row0 * 2) * 64 + slot,        (char*)&Ks[buf][0] + w * 1024);
        gload_lds16(Kb + (k2 + (row0 + 32) * 2) * 64 + slot, (char*)&Ks[buf][0] + 4096 + w * 1024);
        gload_lds16(Vb + (long)row0 * 2048 + k2 + slot,        (char*)&Vs[buf][0] + w * 1024);
        gload_lds16(Vb + (long)(row0 + 32) * 2048 + k2 + slot, (char*)&Vs[buf][0] + 4096 + w * 1024);
    };

    bf16x8 qf[2];
    #pragma unroll
    for (int kc = 0; kc < 2; ++kc)
        qf[kc] = ld_frag(Q + (long)(qbase + lcol) * 64 + kc * 32 + lrow * 8);

    f32x4 acc[4] = {};
    float m_i = NEG;
    float l0 = 0.f, l1 = 0.f;

    STAGE(0, 0);
    STAGE(1, 64);

    for (int tt = 0; tt < T; ++tt) {
        if (tt + 1 < T) asm volatile("s_waitcnt vmcnt(4)" ::: "memory");
        else            asm volatile("s_waitcnt vmcnt(0)" ::: "memory");
        __builtin_amdgcn_s_barrier();          // tile tt landed for all waves

        int cur = tt & 1;
        #pragma unroll
        for (int ks = 0; ks < 2; ++ks) {
            int kt_sub = tt * 64 + ks * 32;
            if (kt_sub < qbase + 16) {         // any key in subtile is <= some q
                bf16x8 kf[2][2], vf[4];
                #pragma unroll
                for (int kg = 0; kg < 2; ++kg)
                    #pragma unroll
                    for (int kc = 0; kc < 2; ++kc) {
                        int row = ks * 32 + kg * 16 + lcol;
                        kf[kg][kc] = ld_frag(&Ks[cur][row * 64 + (((kc * 4 + lrow) ^ (row & 7)) << 3)]);
                    }
                #pragma unroll
                for (int dg = 0; dg < 4; ++dg) {
                    int row = dg * 16 + lcol;
                    vf[dg] = ld_frag(&Vs[cur][row * 64 + (((ks * 4 + lrow) ^ (row & 7)) << 3)]);
                }

                f32x4 s[2] = {};
                __builtin_amdgcn_s_setprio(1);
                #pragma unroll
                for (int kg = 0; kg < 2; ++kg)
                    #pragma unroll
                    for (int kc = 0; kc < 2; ++kc)
                        s[kg] = __builtin_amdgcn_mfma_f32_16x16x32_bf16(kf[kg][kc], qf[kc], s[kg], 0, 0, 0);
                __builtin_amdgcn_s_setprio(0);

                if (kt_sub + 31 > qbase) {
                    #pragma unroll
                    for (int kg = 0; kg < 2; ++kg)
                        #pragma unroll
                        for (int r = 0; r < 4; ++r)
                            if (kt_sub + kg * 16 + lrow * 4 + r > qbase + lcol)
                                s[kg][r] = NEG;
                }
                float a0 = fmaxf(s[0][0], s[0][1]), a1 = fmaxf(s[0][2], s[0][3]);
                float a2 = fmaxf(s[1][0], s[1][1]), a3 = fmaxf(s[1][2], s[1][3]);
                float lmax = fmaxf(fmaxf(a0, a1), fmaxf(a2, a3));
                bool ok = (lmax <= m_i + DEFER_THR);
                if (!__all(ok)) {
                    float mx = fmaxf(lmax, __shfl_xor(lmax, 16));
                    mx = fmaxf(mx, __shfl_xor(mx, 32));
                    float mnew = fmaxf(m_i, mx);
                    float alpha = exp2f(m_i - mnew);
                    m_i = mnew;
                    l0 *= alpha; l1 *= alpha;
                    #pragma unroll
                    for (int dg = 0; dg < 4; ++dg)
                        #pragma unroll
                        for (int r = 0; r < 4; ++r)
                            acc[dg][r] *= alpha;
                }
                float p[8];
                #pragma unroll
                for (int kg = 0; kg < 2; ++kg)
                    #pragma unroll
                    for (int r = 0; r < 4; ++r)
                        p[kg * 4 + r] = exp2f(s[kg][r] - m_i);
                l0 += (p[0] + p[1]) + (p[2] + p[3]);
                l1 += (p[4] + p[5]) + (p[6] + p[7]);
                unsigned u0 = cvtpk_bf16(p[0], p[1]);
                unsigned u1 = cvtpk_bf16(p[2], p[3]);
                unsigned u2 = cvtpk_bf16(p[4], p[5]);
                unsigned u3 = cvtpk_bf16(p[6], p[7]);
                *(uint2*)&Ps[w][lcol][lrow * 4]      = make_uint2(u0, u1);
                *(uint2*)&Ps[w][lcol][16 + lrow * 4] = make_uint2(u2, u3);

                bf16x8 pb = ld_frag(&Ps[w][lcol][lrow * 8]);

                __builtin_amdgcn_s_setprio(1);
                #pragma unroll
                for (int dg = 0; dg < 4; ++dg)
                    acc[dg] = __builtin_amdgcn_mfma_f32_16x16x32_bf16(vf[dg], pb, acc[dg], 0, 0, 0);
                __builtin_amdgcn_s_setprio(0);
            }
        }

        __builtin_amdgcn_s_barrier();          // all reads of buf[cur] done
        if (tt + 2 < T) STAGE(cur, (tt + 2) * 64);
    }

    {
        float lr = l0 + l1;
        lr += __shfl_xor(lr, 16);
        lr += __shfl_xor(lr, 32);
        float inv = 1.f / lr;
        int q = qbase + lcol;
        #pragma unroll
        for (int dg = 0; dg < 4; ++dg) {
            ushort4 pk;
            pk.x = f2bf(acc[dg][0] * inv);
            pk.y = f2bf(acc[dg][1] * inv);
            pk.z = f2bf(acc[dg][2] * inv);
            pk.w = f2bf(acc[dg][3] * inv);
            *(ushort4*)&O[(long)q * 64 + dg * 16 + lrow * 4] = pk;
        }
    }
}

extern "C" void kernel_launch(void* const* d_in, const int* in_sizes, int n_in,
                              void* d_out, int out_size, void* d_ws, size_t ws_size,
                              hipStream_t stream) {
    const float* x    = (const float*)d_in[0];
    const float* Wqkv = (const float*)d_in[1];
    const float* bqkv = (const float*)d_in[2];
    const float* Wfc  = (const float*)d_in[3];
    const float* bfc  = (const float*)d_in[4];
    float* out = (float*)d_out;

    unsigned short* ws    = (unsigned short*)d_ws;
    unsigned short* xb    = ws;                    // 4M elems; dead after gemm<0>
    unsigned short* wqkvT = xb + (4u << 20);       // 3M
    unsigned short* wfcT  = wqkvT + (3u << 20);    // 1M
    unsigned short* qb    = wfcT + (1u << 20);     // 4M
    unsigned short* kb    = qb + (4u << 20);       // 4M
    unsigned short* vb    = kb + (4u << 20);       // 4M; dead after transpose_v
    unsigned short* vbT   = xb;                    // reuse xb
    unsigned short* ob    = vb;                    // reuse vb
    // total ws: 40 MB

    prep<<<dim3(5120), dim3(256), 0, stream>>>(x, xb, Wqkv, wqkvT, Wfc, wfcT);
    gemm128<0><<<dim3(768), dim3(256), 0, stream>>>(xb, wqkvT, bqkv, qb, kb, vb, nullptr);
    transpose_v<<<dim3(32, 2, 64), dim3(32, 8), 0, stream>>>(vb, vbT);
    attn<<<dim3(1024), dim3(256), 0, stream>>>(qb, kb, vbT, ob);
    gemm128<1><<<dim3(256), dim3(256), 0, stream>>>(ob, wfcT, bfc, nullptr, nullptr, nullptr, out);
}

// Round 23
// 100.813 us; speedup vs baseline: 1.0210x; 1.0210x over previous
//
#include <hip/hip_runtime.h>

// B=4, N=1024, E=1024, H=16, D=64.  bf16 MFMA (16x16x32), fp32 accum.
// Raw-reshape: per batch-head bh, Q/K/V slab = flat [bh*65536, +65536) viewed [1024 n][64 d].
// GEMMs (r23): 128x128 tile, EIGHT waves/block (512 thr) — wave owns 64x32 (acc 32 VGPR),
// 1 gload_lds call/matrix/tile (512 lanes x 16B = 8KB), 3-buffer ring depth-2
// (vmcnt(4) steady, tail 2->0), granule-XOR swizzle (T2), setprio (T5), r21 bijective
// XCD swizzle (r22's 2D chunking was neutral — reverted). 3 blocks x 8 waves = 24 waves/CU
// (2x residency vs r21 — the lever that has paid all session: r5, r20).
// Q PRE-SCALED by 0.125*log2(e) -> exp2 softmax. transpose_v builds V^T per head.
// Attention (r20, unchanged): 16 q-rows/wave, 64-row panels, 1024 blocks (4/CU),
// K/V^T in double-buffered LDS (counted vmcnt(4)), XOR-swizzled ds_read_b128,
// no split-K/merge, LPT + XCD pinning.

typedef __bf16 bf16x8 __attribute__((ext_vector_type(8)));
typedef float f32x4 __attribute__((ext_vector_type(4)));

#define QSCALE 0.18033688011112042f   // 0.125 * log2(e)
#define DEFER_THR 11.0f               // log2 domain; P bounded by 2^11

__device__ __forceinline__ unsigned short f2bf(float f) {
    unsigned u = __float_as_uint(f);
    u += 0x7fffu + ((u >> 16) & 1u);   // round-to-nearest-even
    return (unsigned short)(u >> 16);
}

__device__ __forceinline__ unsigned cvtpk_bf16(float lo, float hi) {
    unsigned r;
    asm("v_cvt_pk_bf16_f32 %0, %1, %2" : "=v"(r) : "v"(lo), "v"(hi));
    return r;
}

union FragU { uint4 u; bf16x8 v; };

__device__ __forceinline__ bf16x8 ld_frag(const unsigned short* p) {
    FragU x; x.u = *(const uint4*)p; return x.v;
}

__device__ __forceinline__ void gload_lds16(const void* g, void* l) {
    __builtin_amdgcn_global_load_lds(
        (const __attribute__((address_space(1))) void*)g,
        (__attribute__((address_space(3))) void*)l, 16, 0, 0);
}

// ---------------- fused prep: x->bf16 + both weight transposes (one launch) ----------------
__global__ __launch_bounds__(256) void prep(
    const float* __restrict__ x,    unsigned short* __restrict__ xb,
    const float* __restrict__ Wqkv, unsigned short* __restrict__ wqkvT,
    const float* __restrict__ Wfc,  unsigned short* __restrict__ wfcT)
{
    __shared__ float tile[32][33];
    int bid = blockIdx.x;
    int tx = threadIdx.x & 31, ty = threadIdx.x >> 5;   // (32,8)
    if (bid < 3072) {
        int c0 = (bid % 96) * 32, r0 = (bid / 96) * 32;
        for (int i = ty; i < 32; i += 8)
            tile[i][tx] = Wqkv[(r0 + i) * 3072 + c0 + tx];
        __syncthreads();
        for (int i = ty; i < 32; i += 8)
            wqkvT[(long)(c0 + i) * 1024 + r0 + tx] = f2bf(tile[tx][i]);
    } else if (bid < 4096) {
        int b2 = bid - 3072;
        int c0 = (b2 % 32) * 32, r0 = (b2 / 32) * 32;
        for (int i = ty; i < 32; i += 8)
            tile[i][tx] = Wfc[(r0 + i) * 1024 + c0 + tx];
        __syncthreads();
        for (int i = ty; i < 32; i += 8)
            wfcT[(long)(c0 + i) * 1024 + r0 + tx] = f2bf(tile[tx][i]);
    } else {
        const int n4 = 1 << 20;
        for (int i = (bid - 4096) * 256 + threadIdx.x; i < n4; i += 1024 * 256) {
            float4 f = ((const float4*)x)[i];
            unsigned a = (unsigned)f2bf(f.x) | ((unsigned)f2bf(f.y) << 16);
            unsigned b = (unsigned)f2bf(f.z) | ((unsigned)f2bf(f.w) << 16);
            ((uint2*)xb)[i] = make_uint2(a, b);
        }
    }
}

// ---------------- per-head V transpose: [1024 n][64 d] -> [64 d][1024 n] ----------------
__global__ void transpose_v(const unsigned short* __restrict__ v,
                            unsigned short* __restrict__ vt) {
    __shared__ unsigned short tile[32][33];
    int bh = blockIdx.z;
    int n0 = blockIdx.x * 32, d0 = blockIdx.y * 32;
    const unsigned short* src = v + (long)bh * 65536;
    unsigned short* dst = vt + (long)bh * 65536;
    for (int i = threadIdx.y; i < 32; i += 8)
        tile[i][threadIdx.x] = src[(n0 + i) * 64 + d0 + threadIdx.x];
    __syncthreads();
    for (int i = threadIdx.y; i < 32; i += 8)
        dst[(d0 + i) * 1024 + n0 + threadIdx.x] = tile[threadIdx.x][i];
}

// ---------------- bf16 GEMM, 128x128 tile, 8 waves, 3-buffer ring (depth-2) ----------------
// Wave w (0..7): wm = w>>2 (M half), wn = w&3 (N quarter); owns 64x32 of C, acc[4][2].
// Per K-step: vmcnt(4) [tile t landed; t+1,t+2 in flight] -> barrier -> ds_read(swizzled)
// + MFMA(setprio) -> barrier [reads done] -> STAGE(t+3) into just-read buffer.
template <int MODE>
__global__ __launch_bounds__(512) void gemm128(
    const unsigned short* __restrict__ A,    // [M,1024] bf16
    const unsigned short* __restrict__ Bt,   // [N,1024] bf16
    const float* __restrict__ bias,          // [N]
    unsigned short* __restrict__ qb,
    unsigned short* __restrict__ kb,
    unsigned short* __restrict__ vb,
    float* __restrict__ outf)
{
    __shared__ unsigned short As[3][4096];   // [128 rows][32 k], rows = 64B = 4 granules
    __shared__ unsigned short Bs[3][4096];
    int t = threadIdx.x, lane = t & 63, w = t >> 6;   // w in 0..7
    int wm = w >> 2, wn = w & 3;
    int lrow = lane >> 4, lcol = lane & 15;

    const int NX  = (MODE == 0) ? 24 : 8;
    const int CPX = (MODE == 0) ? 96 : 32;
    int id = blockIdx.x;
    int idp = (id & 7) * CPX + (id >> 3);    // bijective XCD swizzle (grid % 8 == 0)
    int tn0 = (idp % NX) * 128, tm0 = (idp / NX) * 128;

    // staging: 512 lanes x 16B = 8KB = full tile in ONE call per matrix
    int off0 = w * 1024 + lane * 16;         // bytes within tile
    int r0 = off0 >> 6, g0 = ((((off0 >> 4) & 3) ^ ((r0 >> 1) & 3)) << 4);

    const char* pA0 = (const char*)A  + (long)(tm0 + r0) * 2048 + g0;
    const char* pB0 = (const char*)Bt + (long)(tn0 + r0) * 2048 + g0;

    int aoff[4], boff[2];
    #pragma unroll
    for (int mi = 0; mi < 4; ++mi) {
        int row = wm * 64 + mi * 16 + lcol;
        aoff[mi] = row * 32 + ((lrow ^ ((row >> 1) & 3)) << 3);
    }
    #pragma unroll
    for (int ni = 0; ni < 2; ++ni) {
        int row = wn * 32 + ni * 16 + lcol;
        boff[ni] = row * 32 + ((lrow ^ ((row >> 1) & 3)) << 3);
    }

    f32x4 acc[4][2] = {};

    auto STAGE = [&](int buf, int kt) {
        long kby = (long)kt * 2;
        gload_lds16(pA0 + kby, (char*)&As[buf][0] + off0 - lane * 16 + (lane * 16 & 1023) + ((lane * 16) >> 10) * 0);
        gload_lds16(pB0 + kby, (char*)&Bs[buf][0] + off0 - lane * 16 + (lane * 16 & 1023) + ((lane * 16) >> 10) * 0);
    };
    // NOTE: dest must be wave-uniform base; lane*16 is implicit. Simplify:
    auto STAGE2 = [&](int buf, int kt) {
        long kby = (long)kt * 2;
        gload_lds16(pA0 + kby, (char*)&As[buf][0] + w * 1024);
        gload_lds16(pB0 + kby, (char*)&Bs[buf][0] + w * 1024);
    };

    STAGE2(0, 0);
    STAGE2(1, 32);
    STAGE2(2, 64);

    int cur = 0;
    for (int tt = 0; tt < 32; ++tt) {
        // in flight at top: tiles tt (2 calls, oldest), tt+1 (2), tt+2 (2)
        if (tt < 30)      asm volatile("s_waitcnt vmcnt(4)" ::: "memory");
        else if (tt == 30) asm volatile("s_waitcnt vmcnt(2)" ::: "memory");
        else               asm volatile("s_waitcnt vmcnt(0)" ::: "memory");
        __builtin_amdgcn_s_barrier();          // tile tt landed for all waves

        bf16x8 af[4], bfr[2];
        #pragma unroll
        for (int mi = 0; mi < 4; ++mi) af[mi] = ld_frag(&As[cur][aoff[mi]]);
        #pragma unroll
        for (int ni = 0; ni < 2; ++ni) bfr[ni] = ld_frag(&Bs[cur][boff[ni]]);
        __builtin_amdgcn_s_setprio(1);
        #pragma unroll
        for (int mi = 0; mi < 4; ++mi)
            #pragma unroll
            for (int ni = 0; ni < 2; ++ni)
                acc[mi][ni] = __builtin_amdgcn_mfma_f32_16x16x32_bf16(af[mi], bfr[ni], acc[mi][ni], 0, 0, 0);
        __builtin_amdgcn_s_setprio(0);

        __builtin_amdgcn_s_barrier();          // all reads of buf[cur] done
        if (tt + 3 < 32) STAGE2(cur, (tt + 3) * 32);
        cur = (cur == 2) ? 0 : cur + 1;
    }

    #pragma unroll
    for (int mi = 0; mi < 4; ++mi) {
        int gr0 = tm0 + wm * 64 + mi * 16 + lrow * 4;
        #pragma unroll
        for (int ni = 0; ni < 2; ++ni) {
            int gc = tn0 + wn * 32 + ni * 16 + lcol;
            float bv = bias[gc];
            if (MODE == 0) {
                int sec = gc >> 10, ei = gc & 1023;
                unsigned short* dst = sec == 0 ? qb : (sec == 1 ? kb : vb);
                if (sec == 0) {
                    #pragma unroll
                    for (int r = 0; r < 4; ++r)
                        dst[(long)(gr0 + r) * 1024 + ei] = f2bf((acc[mi][ni][r] + bv) * QSCALE);
                } else {
                    #pragma unroll
                    for (int r = 0; r < 4; ++r)
                        dst[(long)(gr0 + r) * 1024 + ei] = f2bf(acc[mi][ni][r] + bv);
                }
            } else {
                #pragma unroll
                for (int r = 0; r < 4; ++r)
                    outf[(long)(gr0 + r) * 1024 + gc] = acc[mi][ni][r] + bv;
            }
        }
    }
}

// ---------------- flash attention: shared-LDS K/V walk, 4 waves x 16 q-rows (r20) ----------------
__global__ __launch_bounds__(256) void attn(
    const unsigned short* __restrict__ qbuf,
    const unsigned short* __restrict__ kbuf,
    const unsigned short* __restrict__ vtbuf,
    unsigned short* __restrict__ obuf)
{
    __shared__ unsigned short Ks[2][4096];   // [64 k][64 d], swizzled
    __shared__ unsigned short Vs[2][4096];   // [64 d][64 k], swizzled
    __shared__ unsigned short Ps[4][16][40]; // per-wave P (16 q-rows)

    int id = blockIdx.x;
    int xcd = id & 7, s_ = id >> 3;          // s_ in 0..127
    int j  = 15 - (s_ >> 3);                 // panels descending (LPT: long first)
    int bh = xcd + 8 * (s_ & 7);             // bh pinned to XCD

    const char* Kb = (const char*)(kbuf + (long)bh * 65536);
    const char* Vb = (const char*)(vtbuf + (long)bh * 65536);
    const unsigned short* Q = qbuf + (long)bh * 65536;
    unsigned short* O = obuf + (long)bh * 65536;

    int t = threadIdx.x, lane = t & 63, w = t >> 6;
    int lrow = lane >> 4, lcol = lane & 15;
    const float NEG = -__builtin_inff();

    int qbase = j * 64 + w * 16;             // wave's 16 q-rows
    int T = j + 1;                           // 64-key tiles for this panel

    int row0 = w * 8 + (lane >> 3);
    int slot = (((lane & 7) ^ (lane >> 3)) << 4);

    auto STAGE = [&](int buf, int kt) {
        long k2 = (long)kt * 2;
        gload_lds16(Kb + (k2 + row0 * 2) * 64 + slot,        (char*)&Ks[buf][0] + w * 1024);
        gload_lds16(Kb + (k2 + (row0 + 32) * 2) * 64 + slot, (char*)&Ks[buf][0] + 4096 + w * 1024);
        gload_lds16(Vb + (long)row0 * 2048 + k2 + slot,        (char*)&Vs[buf][0] + w * 1024);
        gload_lds16(Vb + (long)(row0 + 32) * 2048 + k2 + slot, (char*)&Vs[buf][0] + 4096 + w * 1024);
    };

    bf16x8 qf[2];
    #pragma unroll
    for (int kc = 0; kc < 2; ++kc)
        qf[kc] = ld_frag(Q + (long)(qbase + lcol) * 64 + kc * 32 + lrow * 8);

    f32x4 acc[4] = {};
    float m_i = NEG;
    float l0 = 0.f, l1 = 0.f;

    STAGE(0, 0);
    STAGE(1, 64);

    for (int tt = 0; tt < T; ++tt) {
        if (tt + 1 < T) asm volatile("s_waitcnt vmcnt(4)" ::: "memory");
        else            asm volatile("s_waitcnt vmcnt(0)" ::: "memory");
        __builtin_amdgcn_s_barrier();          // tile tt landed for all waves

        int cur = tt & 1;
        #pragma unroll
        for (int ks = 0; ks < 2; ++ks) {
            int kt_sub = tt * 64 + ks * 32;
            if (kt_sub < qbase + 16) {         // any key in subtile is <= some q
                bf16x8 kf[2][2], vf[4];
                #pragma unroll
                for (int kg = 0; kg < 2; ++kg)
                    #pragma unroll
                    for (int kc = 0; kc < 2; ++kc) {
                        int row = ks * 32 + kg * 16 + lcol;
                        kf[kg][kc] = ld_frag(&Ks[cur][row * 64 + (((kc * 4 + lrow) ^ (row & 7)) << 3)]);
                    }
                #pragma unroll
                for (int dg = 0; dg < 4; ++dg) {
                    int row = dg * 16 + lcol;
                    vf[dg] = ld_frag(&Vs[cur][row * 64 + (((ks * 4 + lrow) ^ (row & 7)) << 3)]);
                }

                f32x4 s[2] = {};
                __builtin_amdgcn_s_setprio(1);
                #pragma unroll
                for (int kg = 0; kg < 2; ++kg)
                    #pragma unroll
                    for (int kc = 0; kc < 2; ++kc)
                        s[kg] = __builtin_amdgcn_mfma_f32_16x16x32_bf16(kf[kg][kc], qf[kc], s[kg], 0, 0, 0);
                __builtin_amdgcn_s_setprio(0);

                if (kt_sub + 31 > qbase) {
                    #pragma unroll
                    for (int kg = 0; kg < 2; ++kg)
                        #pragma unroll
                        for (int r = 0; r < 4; ++r)
                            if (kt_sub + kg * 16 + lrow * 4 + r > qbase + lcol)
                                s[kg][r] = NEG;
                }
                float a0 = fmaxf(s[0][0], s[0][1]), a1 = fmaxf(s[0][2], s[0][3]);
                float a2 = fmaxf(s[1][0], s[1][1]), a3 = fmaxf(s[1][2], s[1][3]);
                float lmax = fmaxf(fmaxf(a0, a1), fmaxf(a2, a3));
                bool ok = (lmax <= m_i + DEFER_THR);
                if (!__all(ok)) {
                    float mx = fmaxf(lmax, __shfl_xor(lmax, 16));
                    mx = fmaxf(mx, __shfl_xor(mx, 32));
                    float mnew = fmaxf(m_i, mx);
                    float alpha = exp2f(m_i - mnew);
                    m_i = mnew;
                    l0 *= alpha; l1 *= alpha;
                    #pragma unroll
                    for (int dg = 0; dg < 4; ++dg)
                        #pragma unroll
                        for (int r = 0; r < 4; ++r)
                            acc[dg][r] *= alpha;
                }
                float p[8];
                #pragma unroll
                for (int kg = 0; kg < 2; ++kg)
                    #pragma unroll
                    for (int r = 0; r < 4; ++r)
                        p[kg * 4 + r] = exp2f(s[kg][r] - m_i);
                l0 += (p[0] + p[1]) + (p[2] + p[3]);
                l1 += (p[4] + p[5]) + (p[6] + p[7]);
                unsigned u0 = cvtpk_bf16(p[0], p[1]);
                unsigned u1 = cvtpk_bf16(p[2], p[3]);
                unsigned u2 = cvtpk_bf16(p[4], p[5]);
                unsigned u3 = cvtpk_bf16(p[6], p[7]);
                *(uint2*)&Ps[w][lcol][lrow * 4]      = make_uint2(u0, u1);
                *(uint2*)&Ps[w][lcol][16 + lrow * 4] = make_uint2(u2, u3);

                bf16x8 pb = ld_frag(&Ps[w][lcol][lrow * 8]);

                __builtin_amdgcn_s_setprio(1);
                #pragma unroll
                for (int dg = 0; dg < 4; ++dg)
                    acc[dg] = __builtin_amdgcn_mfma_f32_16x16x32_bf16(vf[dg], pb, acc[dg], 0, 0, 0);
                __builtin_amdgcn_s_setprio(0);
            }
        }

        __builtin_amdgcn_s_barrier();          // all reads of buf[cur] done
        if (tt + 2 < T) STAGE(cur, (tt + 2) * 64);
    }

    {
        float lr = l0 + l1;
        lr += __shfl_xor(lr, 16);
        lr += __shfl_xor(lr, 32);
        float inv = 1.f / lr;
        int q = qbase + lcol;
        #pragma unroll
        for (int dg = 0; dg < 4; ++dg) {
            ushort4 pk;
            pk.x = f2bf(acc[dg][0] * inv);
            pk.y = f2bf(acc[dg][1] * inv);
            pk.z = f2bf(acc[dg][2] * inv);
            pk.w = f2bf(acc[dg][3] * inv);
            *(ushort4*)&O[(long)q * 64 + dg * 16 + lrow * 4] = pk;
        }
    }
}

extern "C" void kernel_launch(void* const* d_in, const int* in_sizes, int n_in,
                              void* d_out, int out_size, void* d_ws, size_t ws_size,
                              hipStream_t stream) {
    const float* x    = (const float*)d_in[0];
    const float* Wqkv = (const float*)d_in[1];
    const float* bqkv = (const float*)d_in[2];
    const float* Wfc  = (const float*)d_in[3];
    const float* bfc  = (const float*)d_in[4];
    float* out = (float*)d_out;

    unsigned short* ws    = (unsigned short*)d_ws;
    unsigned short* xb    = ws;                    // 4M elems; dead after gemm<0>
    unsigned short* wqkvT = xb + (4u << 20);       // 3M
    unsigned short* wfcT  = wqkvT + (3u << 20);    // 1M
    unsigned short* qb    = wfcT + (1u << 20);     // 4M
    unsigned short* kb    = qb + (4u << 20);       // 4M
    unsigned short* vb    = kb + (4u << 20);       // 4M; dead after transpose_v
    unsigned short* vbT   = xb;                    // reuse xb
    unsigned short* ob    = vb;                    // reuse vb
    // total ws: 40 MB

    prep<<<dim3(5120), dim3(256), 0, stream>>>(x, xb, Wqkv, wqkvT, Wfc, wfcT);
    gemm128<0><<<dim3(768), dim3(512), 0, stream>>>(xb, wqkvT, bqkv, qb, kb, vb, nullptr);
    transpose_v<<<dim3(32, 2, 64), dim3(32, 8), 0, stream>>>(vb, vbT);
    attn<<<dim3(1024), dim3(256), 0, stream>>>(qb, kb, vbT, ob);
    gemm128<1><<<dim3(256), dim3(512), 0, stream>>>(ob, wfcT, bfc, nullptr, nullptr, nullptr, out);
}